// Round 1
// 204.082 us; speedup vs baseline: 1.0430x; 1.0430x over previous
//
#include <hip/hip_runtime.h>

// PWC-Net correlation: out[b, dy*9+dx, y, x] =
//   (1/C) * sum_c first[b,c,y,x] * second[b,c, y+dy-4, x+dx-4]  (zero-padded)
// B=8, C=128, H=W=128.
//
// Round 6: raise FMA-per-LDS-read (XT=8 outputs/thread in x, YB=4 rows/wave)
// to cut the LDS-pipe floor 46->35us and halve per-FMA VALU overhead.
// LDS rows padded to 132 floats (conflict-free at 32B x-steps); padding is
// legal with global_load_lds because staging is per-row half-wave DMAs
// (512B each, dest linear within a row). XCD-aware block swizzle maps each
// batch b to one XCD (768 blocks = 8 XCDs x 96): all 96 blocks of a batch
// are co-resident on the XCD's 32 CUs (3/CU), so dg-siblings and
// y-neighbors share first/second rows in the XCD-private L2
// (FETCH 261MB -> ~135MB; first was fetched 3x before).

#define B  8
#define C  128
#define H  128
#define W  128
#define CC 4
#define YB 4
#define XT 8
#define NTHR 192
#define NCHUNK (C / CC)        // 32
#define SROWS 6                // second rows per dy-group (yi 0..3 + w 0..2)
#define WP (W + 4)             // padded LDS row stride (floats)
#define CHSTRIDE (CC * H * W)  // 65536 floats per chunk step

typedef const void __attribute__((address_space(1)))* gvp;
typedef void __attribute__((address_space(3)))* lvp;

__device__ __forceinline__ void dma16(const float* g, float* l) {
    __builtin_amdgcn_global_load_lds((gvp)g, (lvp)l, 16, 0, 0);
}

__global__ __launch_bounds__(NTHR) __attribute__((amdgpu_waves_per_eu(3)))
void ModuleCorrelation_41970420416706_kernel(const float* __restrict__ first,
                                             const float* __restrict__ second,
                                             float* __restrict__ out) {
    __shared__ __align__(16) float sFirst[2][CC][YB][WP];     // 16.5 KiB
    __shared__ __align__(16) float sSec[2][CC][SROWS][WP];    // 24.75 KiB

    // ---- XCD swizzle: phys blocks round-robin XCDs, so give XCD k the
    //      contiguous logical range [k*96, k*96+96) == all of batch b=k ----
    const int phys = blockIdx.x;
    const int l    = (phys & 7) * 96 + (phys >> 3);   // 768 = 8*96, bijective
    const int b    = l / 96;
    const int rem  = l - b * 96;
    const int y0   = (rem / 3) * YB;
    const int dg   = rem - (rem / 3) * 3;    // dg fastest: siblings adjacent
    const int d0   = dg * 3;                 // dy group base: 0, 3, 6

    const int t    = threadIdx.x;
    const int w    = t >> 6;                 // wave = dy - d0, in [0,3)
    const int lane = t & 63;
    const int yi   = lane >> 4;              // 0..3
    const int xt   = lane & 15;              // 0..15
    const int x0   = xt * XT;                // 0,8,...,120

    const float* firstB  = first  + (size_t)b * C * H * W;
    const float* secondB = second + (size_t)b * C * H * W;

    // ---- pre-zero sSec rows whose source y is OOB (chunk-invariant) ----
    {
        const float4 z4 = make_float4(0.f, 0.f, 0.f, 0.f);
        for (int idx = t; idx < 2 * CC * SROWS * (W / 4); idx += NTHR) {  // 1536
            const int r2 = idx >> 5;         // row id 0..47
            const int xq = idx & 31;
            const int rr = r2 % SROWS;
            const int ys = y0 + d0 - 4 + rr;
            if (ys < 0 || ys >= H) {
                const int buf = r2 / (CC * SROWS);
                const int c   = (r2 / SROWS) % CC;
                *(float4*)&sSec[buf][c][rr][xq * 4] = z4;
            }
        }
    }

    // ---- async staging: per-row half-wave DMAs (512B), padded LDS rows.
    //      wave2: 16 first rows; waves 0,1: 12 second rows each ----
    auto stage = [&](int buf, int chunk) {
        const int off = chunk * CHSTRIDE;
        if (w == 2) {
            if (lane < 32) {
#pragma unroll
                for (int i = 0; i < 16; ++i) {       // c = i>>2, row = i&3
                    const int c = i >> 2, r = i & 3;
                    dma16(firstB + off + (c * H + y0 + r) * W + lane * 4,
                          &sFirst[buf][c][r][0]);
                }
            }
        } else if (lane < 32) {
#pragma unroll
            for (int i = 0; i < 12; ++i) {
                const int c  = w * 2 + i / 6;        // wave-uniform
                const int rr = i % 6;
                const int ys = y0 + d0 - 4 + rr;
                if (ys >= 0 && ys < H)               // wave-uniform
                    dma16(secondB + off + (c * H + ys) * W + lane * 4,
                          &sSec[buf][c][rr][0]);
            }
        }
    };

    float acc[9][XT];
#pragma unroll
    for (int dx = 0; dx < 9; ++dx)
#pragma unroll
        for (int j = 0; j < XT; ++j) acc[dx][j] = 0.f;

    stage(0, 0);
    __syncthreads();                 // buf0 staged (vmcnt drained) + zeros visible

    const bool edgeL = (xt == 0);
    const bool edgeR = (xt == 15);
    const int offA = edgeL ? 0 : x0 - 4;      // clamped aligned read, masked below
    const int offC = edgeR ? x0 + 4 : x0 + 8;
    const int fOff = yi * WP + x0;
    const int sOff = (yi + w) * WP;           // rr = yi + w

    for (int k = 0; k < NCHUNK; ++k) {
        const int buf = k & 1;
        if (k + 1 < NCHUNK) stage(buf ^ 1, k + 1);   // lands during compute

        const float* sF = &sFirst[buf][0][0][0];
        const float* sS = &sSec[buf][0][0][0];
#pragma unroll
        for (int c = 0; c < CC; ++c) {
            const float4 f0 = *(const float4*)(sF + c * (YB * WP) + fOff);
            const float4 f1 = *(const float4*)(sF + c * (YB * WP) + fOff + 4);
            const float* sr = sS + c * (SROWS * WP) + sOff;
            float4 A        = *(const float4*)(sr + offA);
            const float4 B0 = *(const float4*)(sr + x0);
            const float4 B1 = *(const float4*)(sr + x0 + 4);
            float4 Cv       = *(const float4*)(sr + offC);
            if (edgeL) { A.x = 0.f; A.y = 0.f; A.z = 0.f; A.w = 0.f; }
            if (edgeR) { Cv.x = 0.f; Cv.y = 0.f; Cv.z = 0.f; Cv.w = 0.f; }
            const float s[16] = {A.x,  A.y,  A.z,  A.w,
                                 B0.x, B0.y, B0.z, B0.w,
                                 B1.x, B1.y, B1.z, B1.w,
                                 Cv.x, Cv.y, Cv.z, Cv.w};
            const float ff[8] = {f0.x, f0.y, f0.z, f0.w,
                                 f1.x, f1.y, f1.z, f1.w};
#pragma unroll
            for (int dx = 0; dx < 9; ++dx)
#pragma unroll
                for (int j = 0; j < XT; ++j)
                    acc[dx][j] += ff[j] * s[dx + j];
        }
        __syncthreads();   // all waves done with buf; stage(k+1) drained
    }

    // ---- epilogue ----
    const float scale = 1.0f / (float)C;
    const int dy = d0 + w;
    const int yOut = y0 + yi;
#pragma unroll
    for (int dx = 0; dx < 9; ++dx) {
        const int tc = dy * 9 + dx;
        float* op = &out[((b * 81 + tc) * H + yOut) * W + x0];
        float4 o0, o1;
        o0.x = acc[dx][0] * scale;
        o0.y = acc[dx][1] * scale;
        o0.z = acc[dx][2] * scale;
        o0.w = acc[dx][3] * scale;
        o1.x = acc[dx][4] * scale;
        o1.y = acc[dx][5] * scale;
        o1.z = acc[dx][6] * scale;
        o1.w = acc[dx][7] * scale;
        *(float4*)op       = o0;
        *(float4*)(op + 4) = o1;
    }
}

extern "C" void kernel_launch(void* const* d_in, const int* in_sizes, int n_in,
                              void* d_out, int out_size, void* d_ws, size_t ws_size,
                              hipStream_t stream) {
    const float* first  = (const float*)d_in[0];
    const float* second = (const float*)d_in[1];
    float* out = (float*)d_out;

    dim3 grid(B * (H / YB) * 3);   // 768 blocks = 8 XCDs x 96 = 3 per CU
    dim3 block(NTHR);              // 192 threads = 3 waves
    ModuleCorrelation_41970420416706_kernel<<<grid, block, 0, stream>>>(first, second, out);
}